// Round 16
// baseline (74.290 us; speedup 1.0000x reference)
//
#include <hip/hip_runtime.h>
#include <hip/hip_bf16.h>
#include <math.h>

#define BN 32
#define L 128
#define D 128
#define TT 127
#define NH 8

typedef float f32x4 __attribute__((ext_vector_type(4)));
typedef short s16x8 __attribute__((ext_vector_type(8)));

__device__ __forceinline__ float gelu_sig(float x) {
    float e = __expf(-1.702f * x);
    return x * __builtin_amdgcn_rcpf(1.0f + e);
}
__device__ __forceinline__ unsigned short f2bf(float f) {
    unsigned u = __float_as_uint(f);
    return (unsigned short)((u + 0x7fffu + ((u >> 16) & 1u)) >> 16);
}
__device__ __forceinline__ float bf2f(unsigned short v) {
    return __uint_as_float((unsigned)v << 16);
}

// ---------------- K1: qkv (blocks 0..383) + bias MLP (blocks 384..2431) ----------------
// Q -> f32 rows. K -> KF (bf16, B-fragment order of K^T). V -> VF (bf16, B-fragment).
__global__ __launch_bounds__(256)
void qkv_bias_kernel(const float* __restrict__ padded, const float* __restrict__ tok,
                     const float* __restrict__ Wq, const float* __restrict__ bq,
                     const float* __restrict__ Wk, const float* __restrict__ bk,
                     const float* __restrict__ Wv, const float* __restrict__ bv,
                     const float* __restrict__ Wb1, const float* __restrict__ bb1,
                     const float* __restrict__ Wb2, const float* __restrict__ bb2,
                     const float* __restrict__ Wv1, const float* __restrict__ bv1,
                     const float* __restrict__ Wv2,
                     const int* __restrict__ masks, const float* __restrict__ pos3d,
                     float* __restrict__ Qo, unsigned short* __restrict__ KF,
                     unsigned short* __restrict__ VF,
                     float* __restrict__ RVW, unsigned short* __restrict__ WV2F,
                     unsigned short* __restrict__ BIAS) {
    const int bid = blockIdx.x;
    const int tid = threadIdx.x;

    if (bid < 384) {
        // ---------------- qkv ----------------
        const int chunk = bid / 96;
        const int rem = bid % 96;
        const int mat = rem >> 5;
        const int s = rem & 31;
        const float* W = (mat == 0) ? Wq : (mat == 1) ? Wk : Wv;
        const float* bias = (mat == 0) ? bq : (mat == 1) ? bk : bv;

        __shared__ __align__(16) unsigned short Xs[32][136];
        {
            const int row = tid >> 3;
            const int colbase = (tid & 7) * 16;
            const int i = chunk * 32 + row;
            const float* src = (i == 0) ? tok : &padded[(size_t)s * TT * D + (size_t)(i - 1) * D];
#pragma unroll
            for (int k4 = 0; k4 < 4; ++k4) {
                float4 v = *(const float4*)&src[colbase + k4 * 4];
                unsigned lo = (unsigned)f2bf(v.x) | ((unsigned)f2bf(v.y) << 16);
                unsigned hi = (unsigned)f2bf(v.z) | ((unsigned)f2bf(v.w) << 16);
                *(uint2*)&Xs[row][colbase + k4 * 4] = make_uint2(lo, hi);
            }
        }
        __syncthreads();

        const int wave = tid >> 6;
        const int lane = tid & 63;
        const int hA = lane & 15;
        const int kg = lane >> 4;

        s16x8 afr[2][4];
#pragma unroll
        for (int m = 0; m < 2; ++m)
#pragma unroll
            for (int kt = 0; kt < 4; ++kt)
                afr[m][kt] = *(const s16x8*)&Xs[m * 16 + hA][kt * 32 + kg * 8];

        f32x4 acc[2][2];
#pragma unroll
        for (int m = 0; m < 2; ++m)
#pragma unroll
            for (int n = 0; n < 2; ++n) acc[m][n] = (f32x4){0.f, 0.f, 0.f, 0.f};

#pragma unroll
        for (int kt = 0; kt < 4; ++kt) {
#pragma unroll
            for (int n = 0; n < 2; ++n) {
                const int col = (2 * wave + n) * 16 + hA;
                s16x8 bw;
#pragma unroll
                for (int e = 0; e < 8; ++e)
                    bw[e] = (short)f2bf(W[(size_t)(kt * 32 + kg * 8 + e) * D + col]);
                acc[0][n] = __builtin_amdgcn_mfma_f32_16x16x32_bf16(afr[0][kt], bw, acc[0][n], 0, 0, 0);
                acc[1][n] = __builtin_amdgcn_mfma_f32_16x16x32_bf16(afr[1][kt], bw, acc[1][n], 0, 0, 0);
            }
        }

        if (mat == 0) {
#pragma unroll
            for (int n = 0; n < 2; ++n) {
                const int col = (2 * wave + n) * 16 + hA;
                const float bc = bias[col];
#pragma unroll
                for (int m = 0; m < 2; ++m)
#pragma unroll
                    for (int r = 0; r < 4; ++r) {
                        const int row = chunk * 32 + m * 16 + kg * 4 + r;
                        Qo[(size_t)s * L * D + (size_t)row * D + col] = acc[m][n][r] + bc;
                    }
            }
        } else {
            // ---- K/V: stage bf16 rows in LDS, then pack to fragment order ----
            __syncthreads();
#pragma unroll
            for (int n = 0; n < 2; ++n) {
                const int col = (2 * wave + n) * 16 + hA;
                const float bc = bias[col];
#pragma unroll
                for (int m = 0; m < 2; ++m)
#pragma unroll
                    for (int r = 0; r < 4; ++r)
                        Xs[m * 16 + kg * 4 + r][col] = f2bf(acc[m][n][r] + bc);
            }
            __syncthreads();
            if (mat == 2) {
#pragma unroll
                for (int pass = 0; pass < 2; ++pass) {
                    const int idx = pass * 256 + tid;
                    const int fl = idx >> 6, ln = idx & 63;
                    unsigned short v8[8];
#pragma unroll
                    for (int e = 0; e < 8; ++e)
                        v8[e] = Xs[(ln >> 4) * 8 + e][fl * 16 + (ln & 15)];
                    *(uint4*)&VF[(size_t)s * 16384 + ((size_t)(chunk * 8 + fl) * 64 + ln) * 8] = *(uint4*)v8;
                }
            } else {
#pragma unroll
                for (int pass = 0; pass < 2; ++pass) {
                    const int idx = pass * 256 + tid;
                    const int lf = idx >> 6, ln = idx & 63;
                    const int kt = lf >> 1, ngl = lf & 1;
                    uint4 v = *(const uint4*)&Xs[ngl * 16 + (ln & 15)][kt * 32 + (ln >> 4) * 8];
                    *(uint4*)&KF[(size_t)s * 16384 + ((size_t)(kt * 8 + 2 * chunk + ngl) * 64 + ln) * 8] = v;
                }
            }
        }

        if (bid == 0) {
            if (tid < 128) {
                const int cc = tid;
                RVW[cc * 8 + 0] = Wv1[0 * 128 + cc];
                RVW[cc * 8 + 1] = Wv1[1 * 128 + cc];
                RVW[cc * 8 + 2] = Wv1[2 * 128 + cc];
                RVW[cc * 8 + 3] = Wv1[3 * 128 + cc] + Wv1[4 * 128 + cc];
                RVW[cc * 8 + 4] = Wv1[5 * 128 + cc];
                RVW[cc * 8 + 5] = bv1[cc];
                RVW[cc * 8 + 6] = 0.f;
                RVW[cc * 8 + 7] = 0.f;
            }
            for (int idx = tid; idx < 16384; idx += 256) {
                int f = idx >> 9, r = idx & 511, ln = r >> 3, e = r & 7;
                int kt = f >> 3, ng = f & 7;
                int row = kt * 32 + (ln >> 4) * 8 + e;
                int col = ng * 16 + (ln & 15);
                WV2F[idx] = f2bf(Wv2[(size_t)row * D + col]);
            }
        }
    } else {
        // ---------------- bias MLP ----------------
        const int b2 = bid - 384;
        const int s = b2 >> 6;
        const int jp = b2 & 63;
        const int wv = tid >> 6;
        const int lane = tid & 63;
        const int j = jp * 2 + (wv >> 1);
        const int i = (wv & 1) * 64 + lane;

        if (j == 0) return;
        if (!masks[(size_t)s * TT + (j - 1)]) return;
        const float* pj = pos3d + ((size_t)s * TT + (j - 1)) * 3;
        const int im1 = (i > 0) ? (i - 1) : 0;
        const float* pi = pos3d + ((size_t)s * TT + im1) * 3;
        const float pix = (i > 0) ? pi[0] : 0.f;
        const float piy = (i > 0) ? pi[1] : 0.f;
        const float piz = (i > 0) ? pi[2] : 0.f;
        const float dx = pix - pj[0], dy = piy - pj[1], dz = piz - pj[2];
        const float dist2 = dx * dx + dy * dy + dz * dz;
        const float dist = sqrtf(dist2);

        float bias[NH];
#pragma unroll
        for (int hh = 0; hh < NH; ++hh) bias[hh] = 0.f;
#pragma unroll 2
        for (int u = 0; u < 64; ++u) {
            const float w0 = Wb1[u];
            const float w1 = Wb1[64 + u];
            const float w2 = Wb1[128 + u];
            const float w3 = Wb1[192 + u] + Wb1[256 + u];
            const float w4 = Wb1[320 + u];
            float hv = bb1[u];
            hv = fmaf(dx, w0, hv);
            hv = fmaf(dy, w1, hv);
            hv = fmaf(dz, w2, hv);
            hv = fmaf(dist, w3, hv);
            hv = fmaf(dist2, w4, hv);
            hv = gelu_sig(hv);
            const float* w2p = &Wb2[u * 8];
            bias[0] = fmaf(hv, w2p[0], bias[0]);
            bias[1] = fmaf(hv, w2p[1], bias[1]);
            bias[2] = fmaf(hv, w2p[2], bias[2]);
            bias[3] = fmaf(hv, w2p[3], bias[3]);
            bias[4] = fmaf(hv, w2p[4], bias[4]);
            bias[5] = fmaf(hv, w2p[5], bias[5]);
            bias[6] = fmaf(hv, w2p[6], bias[6]);
            bias[7] = fmaf(hv, w2p[7], bias[7]);
        }
        if (i > 0) {
            uint4 ow;
            ow.x = (unsigned)f2bf(bias[0] + bb2[0]) | ((unsigned)f2bf(bias[1] + bb2[1]) << 16);
            ow.y = (unsigned)f2bf(bias[2] + bb2[2]) | ((unsigned)f2bf(bias[3] + bb2[3]) << 16);
            ow.z = (unsigned)f2bf(bias[4] + bb2[4]) | ((unsigned)f2bf(bias[5] + bb2[5]) << 16);
            ow.w = (unsigned)f2bf(bias[6] + bb2[6]) | ((unsigned)f2bf(bias[7] + bb2[7]) << 16);
            *(uint4*)&BIAS[(((size_t)s * L + i) * L + j) * 8] = ow;   // i-major
        }
    }
}

// ---------------- K3: core per (s,i). grid (L, BN), block 256 (4 waves), 5 barriers ----------------
__global__ __launch_bounds__(256, 4)
void attn_kernel(const float* __restrict__ padded, const int* __restrict__ masks,
                 const float* __restrict__ pos3d,
                 const float* __restrict__ gamma, const float* __restrict__ beta,
                 const float* __restrict__ tok,
                 const float* __restrict__ RVW,
                 const unsigned short* __restrict__ WV2F,
                 const float* __restrict__ bv2,
                 const float* __restrict__ Q,
                 const unsigned short* __restrict__ KF,
                 const unsigned short* __restrict__ VF,
                 const unsigned short* __restrict__ BIAS,
                 float* __restrict__ out) {
    const int i = blockIdx.x;
    const int s = blockIdx.y;
    const int tid = threadIdx.x;
    const int wave = tid >> 6;
    const int lane = tid & 63;
    const int hA = lane & 15;
    const int kg = lane >> 4;
    const int j = tid & 127;
    const int hbase = (tid >> 7) * 4;

    __shared__ float4 feat4_lds[144];
    __shared__ float  feat5_lds[L];
    __shared__ float  l_lds[NH][132];          // unioned with gs_bf (below)
    __shared__ unsigned short w_bf[NH][136];   // compacted normalized w
    __shared__ unsigned short wu_bf[NH][136];  // uncompacted normalized w
    __shared__ float  a12_lds[2][D];           // [0]=a1, [1]=a2
    __shared__ float  reds[4][NH];
    __shared__ float  red2[2][2];
    __shared__ int    jmap_lds[128];
    unsigned short (*gs_bf)[136] = (unsigned short (*)[136])&l_lds[0][0];  // 2176B <= 4224B

    // ---- masks: every wave computes BOTH half-ballots locally ----
    const int keep0 = (lane == 0) ? 1 : masks[(size_t)s * TT + lane - 1];      // j = lane
    const int keep1 = masks[(size_t)s * TT + lane + 63];                       // j = lane + 64
    const unsigned long long bal0 = __ballot(keep0 != 0);
    const unsigned long long bal1 = __ballot(keep1 != 0);
    const int keep = (wave & 1) ? keep1 : keep0;
    const int nk0 = __popcll(bal0);
    const int nk = nk0 + __popcll(bal1);
    const int NK32 = (nk + 31) >> 5;
    const unsigned long long below = (1ull << lane) - 1;
    int rank, nrank;
    if (wave & 1) { rank = nk0 + __popcll(bal1 & below); nrank = (64 - nk0) + __popcll(~bal1 & below); }
    else          { rank = __popcll(bal0 & below);       nrank = __popcll(~bal0 & below); }

    // filler writes (race-free: disjoint slots; readers are after barrier D)
    if (wave < 2) {
        if (keep) jmap_lds[rank] = j;
        else      jmap_lds[nk + nrank] = 0;
    }
    if (!keep) {
        const int slot = nk + nrank;
#pragma unroll
        for (int k = 0; k < 4; ++k) {
            w_bf[hbase + k][slot] = 0;
            wu_bf[hbase + k][j] = 0;
        }
    }

    // ---- bias load (i-major, coalesced) ----
    const int ub = (i > 0) && (j > 0) && keep;
    uint2 braw = make_uint2(0u, 0u);
    if (ub) braw = *(const uint2*)&BIAS[(((size_t)s * L + i) * L + j) * 8 + hbase];

    // ---- relative features (threads 0-127); ordered w.r.t. readers by barriers B-D ----
    if (tid < 128) {
        float pix = 0.f, piy = 0.f, piz = 0.f;
        if (i > 0) { const float* pp = pos3d + ((size_t)s * TT + (i - 1)) * 3; pix = pp[0]; piy = pp[1]; piz = pp[2]; }
        float pjx = 0.f, pjy = 0.f, pjz = 0.f;
        if (tid > 0) { const float* pp = pos3d + ((size_t)s * TT + (tid - 1)) * 3; pjx = pp[0]; pjy = pp[1]; pjz = pp[2]; }
        const float dx = pix - pjx, dy = piy - pjy, dz = piz - pjz;
        const float dist2 = dx * dx + dy * dy + dz * dz;
        const float dist = sqrtf(dist2);
        feat4_lds[tid + (tid >> 3)] = make_float4(dx, dy, dz, dist);
        feat5_lds[tid] = dist2;
    }

    const int ng0 = 2 * wave;
    const unsigned short* KFs = KF + (size_t)s * 16384;
    const unsigned short* VFs = VF + (size_t)s * 16384;

    // ---- logits via MFMA: A = Q row (direct global load) masked to head slices ----
    {
        f32x4 accL[2];
        accL[0] = (f32x4){0.f, 0.f, 0.f, 0.f};
        accL[1] = (f32x4){0.f, 0.f, 0.f, 0.f};
        const float* Qrow = Q + ((size_t)s * L + i) * D;
#pragma unroll
        for (int kt = 0; kt < 4; ++kt) {
            const int hslice = kt * 2 + (kg >> 1);
            s16x8 qa;
#pragma unroll
            for (int e = 0; e < 8; ++e) qa[e] = 0;
            if (hA == hslice) {
                float4 q0 = *(const float4*)&Qrow[kt * 32 + kg * 8];
                float4 q1 = *(const float4*)&Qrow[kt * 32 + kg * 8 + 4];
                qa[0] = (short)f2bf(q0.x); qa[1] = (short)f2bf(q0.y);
                qa[2] = (short)f2bf(q0.z); qa[3] = (short)f2bf(q0.w);
                qa[4] = (short)f2bf(q1.x); qa[5] = (short)f2bf(q1.y);
                qa[6] = (short)f2bf(q1.z); qa[7] = (short)f2bf(q1.w);
            }
#pragma unroll
            for (int n = 0; n < 2; ++n) {
                s16x8 bk = *(const s16x8*)&KFs[((size_t)(kt * 8 + ng0 + n) * 64 + lane) * 8];
                accL[n] = __builtin_amdgcn_mfma_f32_16x16x32_bf16(qa, bk, accL[n], 0, 0, 0);
            }
        }
        if (lane < 32) {
#pragma unroll
            for (int n = 0; n < 2; ++n)
#pragma unroll
                for (int r = 0; r < 4; ++r)
                    l_lds[(lane >> 4) * 4 + r][(ng0 + n) * 16 + hA] = accL[n][r];
        }
    }
    __syncthreads();                       // B: l_lds + feat ready

    // ---- softmax: 4 heads per thread-half ----
    float badd[4];
    badd[0] = bf2f((unsigned short)(braw.x & 0xffffu));
    badd[1] = bf2f((unsigned short)(braw.x >> 16));
    badd[2] = bf2f((unsigned short)(braw.y & 0xffffu));
    badd[3] = bf2f((unsigned short)(braw.y >> 16));
    float p4[4];
#pragma unroll
    for (int k = 0; k < 4; ++k) {
        float lv = fmaf(l_lds[hbase + k][j], 0.25f, badd[k]);
        p4[k] = keep ? __expf(lv) : 0.f;
    }
#pragma unroll
    for (int k = 0; k < 4; ++k) {
        float v = p4[k];
        for (int off = 32; off >= 1; off >>= 1) v += __shfl_xor(v, off, 64);
        if (lane == 0) reds[wave][hbase + k] = v;
    }
    __syncthreads();                       // C: reds ready (l_lds dead after this)
    if (keep) {
        const int pb = (tid >> 7) * 2;
#pragma unroll
        for (int k = 0; k < 4; ++k) {
            const int hh = hbase + k;
            float inv = __builtin_amdgcn_rcpf(reds[pb][hh] + reds[pb + 1][hh]);
            unsigned short wn = f2bf(p4[k] * inv);
            w_bf[hh][rank] = wn;
            wu_bf[hh][j] = wn;
        }
    }
    __syncthreads();                       // D: w ready

    // ---- a1 = W · V via MFMA (uncompacted w, prepacked V) — all i ----
    f32x4 acc1[2];
    acc1[0] = (f32x4){0.f, 0.f, 0.f, 0.f};
    acc1[1] = (f32x4){0.f, 0.f, 0.f, 0.f};
#pragma unroll
    for (int kt = 0; kt < 4; ++kt) {
        s16x8 wuf;
#pragma unroll
        for (int e = 0; e < 8; ++e) wuf[e] = 0;
        if (hA < NH)
            wuf = *(const s16x8*)&wu_bf[hA][kt * 32 + kg * 8];
#pragma unroll
        for (int n = 0; n < 2; ++n) {
            const int f = kt * 8 + ng0 + n;
            s16x8 bw = *(const s16x8*)&VFs[((size_t)f * 64 + lane) * 8];
            acc1[n] = __builtin_amdgcn_mfma_f32_16x16x32_bf16(wuf, bw, acc1[n], 0, 0, 0);
        }
    }
#pragma unroll
    for (int n = 0; n < 2; ++n) {
        const int f = ng0 + n;
        if (kg == (f >> 2)) a12_lds[0][f * 16 + hA] = acc1[n][f & 3];
    }

    if (i > 0) {
        float rvw[2][6];
#pragma unroll
        for (int n = 0; n < 2; ++n) {
            const int c = (ng0 + n) * 16 + hA;
            float4 ra = *(const float4*)&RVW[(size_t)c * 8 + 0];
            rvw[n][0] = ra.x; rvw[n][1] = ra.y; rvw[n][2] = ra.z; rvw[n][3] = ra.w;
            rvw[n][4] = RVW[(size_t)c * 8 + 4];
            rvw[n][5] = RVW[(size_t)c * 8 + 5];
        }

        f32x4 accG[2];
#pragma unroll
        for (int n = 0; n < 2; ++n) accG[n] = (f32x4){0.f, 0.f, 0.f, 0.f};

#pragma unroll
        for (int kt = 0; kt < 4; ++kt) {
            if (kt >= NK32) break;
            s16x8 wf;
#pragma unroll
            for (int e = 0; e < 8; ++e) wf[e] = 0;
            if (hA < NH) {
                wf = *(const s16x8*)&w_bf[hA][kt * 32 + kg * 8];
                if (kt == 0 && kg == 0) wf[0] = 0;   // exclude j==0 (rank 0)
            }
            s16x8 bfr[2];
#pragma unroll
            for (int e = 0; e < 8; ++e) {
                const int jj = jmap_lds[kt * 32 + kg * 8 + e];
                float4 fa = feat4_lds[jj + (jj >> 3)];
                float f5 = feat5_lds[jj];
#pragma unroll
                for (int n = 0; n < 2; ++n) {
                    float hv = rvw[n][5];
                    hv = fmaf(fa.x, rvw[n][0], hv);
                    hv = fmaf(fa.y, rvw[n][1], hv);
                    hv = fmaf(fa.z, rvw[n][2], hv);
                    hv = fmaf(fa.w, rvw[n][3], hv);
                    hv = fmaf(f5,  rvw[n][4], hv);
                    bfr[n][e] = (short)f2bf(gelu_sig(hv));
                }
            }
#pragma unroll
            for (int n = 0; n < 2; ++n)
                accG[n] = __builtin_amdgcn_mfma_f32_16x16x32_bf16(wf, bfr[n], accG[n], 0, 0, 0);
        }

        // GS rows 0..7 live in lanes 0..31 (D-layout row=(lane>>4)*4+reg)
        if (lane < 32) {
#pragma unroll
            for (int n = 0; n < 2; ++n)
#pragma unroll
                for (int r = 0; r < 4; ++r)
                    gs_bf[(lane >> 4) * 4 + r][(ng0 + n) * 16 + hA] = f2bf(accG[n][r]);
        }
        __syncthreads();                   // E

        // ---- a2 = GS @ Wv2 via MFMA (2 col-frags per wave) ----
        f32x4 acc2[2];
#pragma unroll
        for (int n = 0; n < 2; ++n) acc2[n] = (f32x4){0.f, 0.f, 0.f, 0.f};
#pragma unroll
        for (int kt = 0; kt < 4; ++kt) {
            s16x8 gf;
#pragma unroll
            for (int e = 0; e < 8; ++e) gf[e] = 0;
            if (hA < NH)
                gf = *(const s16x8*)&gs_bf[hA][kt * 32 + kg * 8];
#pragma unroll
            for (int n = 0; n < 2; ++n) {
                const int f = kt * 8 + ng0 + n;
                s16x8 bw = *(const s16x8*)&WV2F[((size_t)f * 64 + lane) * 8];
                acc2[n] = __builtin_amdgcn_mfma_f32_16x16x32_bf16(gf, bw, acc2[n], 0, 0, 0);
            }
        }
#pragma unroll
        for (int n = 0; n < 2; ++n) {
            const int f = ng0 + n;
            if (kg == (f >> 2)) a12_lds[1][f * 16 + hA] = acc2[n][f & 3];
        }
        __syncthreads();                   // F

        if (tid < 128) {
            const float S1 = 1.0f - bf2f(wu_bf[tid >> 4][0]);
            const size_t o = (size_t)s * TT * D + (size_t)(i - 1) * D + tid;
            out[o] = a12_lds[0][tid] + a12_lds[1][tid] + S1 * bv2[tid] + padded[o];
        }
    } else {
        // ---- cls row: a2 == 0; a1 from MFMA + layernorm ----
        __syncthreads();                   // E

        float st = 0.f;
        if (tid < 128) {
            st = a12_lds[0][tid] + tok[tid];
            float sum = st, sum2 = st * st;
            for (int off = 32; off >= 1; off >>= 1) {
                sum += __shfl_xor(sum, off, 64);
                sum2 += __shfl_xor(sum2, off, 64);
            }
            if (lane == 0) { red2[wave][0] = sum; red2[wave][1] = sum2; }
        }
        __syncthreads();                   // F
        if (tid < 128) {
            float sum = red2[0][0] + red2[1][0];
            float sum2 = red2[0][1] + red2[1][1];
            const float mu = sum * (1.0f / 128.0f);
            const float var = sum2 * (1.0f / 128.0f) - mu * mu;
            const float y = (st - mu) * rsqrtf(var + 1e-5f) * gamma[tid] + beta[tid];
            out[(size_t)BN * TT * D + (size_t)s * D + tid] = y;
        }
    }
}

extern "C" void kernel_launch(void* const* d_in, const int* in_sizes, int n_in,
                              void* d_out, int out_size, void* d_ws, size_t ws_size,
                              hipStream_t stream) {
    const float* padded = (const float*)d_in[0];
    const int*   masks  = (const int*)d_in[1];
    const float* pos3d  = (const float*)d_in[2];
    const float* Wq = (const float*)d_in[3];
    const float* bq = (const float*)d_in[4];
    const float* Wk = (const float*)d_in[5];
    const float* bk = (const float*)d_in[6];
    const float* Wv = (const float*)d_in[7];
    const float* bv = (const float*)d_in[8];
    const float* gamma = (const float*)d_in[9];
    const float* beta  = (const float*)d_in[10];
    const float* tok   = (const float*)d_in[11];
    const float* Wb1 = (const float*)d_in[12];
    const float* bb1 = (const float*)d_in[13];
    const float* Wb2 = (const float*)d_in[14];
    const float* bb2 = (const float*)d_in[15];
    const float* Wv1 = (const float*)d_in[16];
    const float* bv1 = (const float*)d_in[17];
    const float* Wv2 = (const float*)d_in[18];
    const float* bv2 = (const float*)d_in[19];
    float* out = (float*)d_out;

    float* Q  = (float*)d_ws;
    unsigned short* KF = (unsigned short*)(Q + (size_t)BN * L * D);
    unsigned short* VF = KF + (size_t)BN * L * D;
    unsigned short* BIAS = VF + (size_t)BN * L * D;
    float* RVW = (float*)(BIAS + (size_t)BN * L * L * NH);
    unsigned short* WV2F = (unsigned short*)(RVW + 128 * 8);

    qkv_bias_kernel<<<dim3(384 + BN * 64), 256, 0, stream>>>(
        padded, tok, Wq, bq, Wk, bk, Wv, bv, Wb1, bb1, Wb2, bb2, Wv1, bv1, Wv2,
        masks, pos3d, Q, KF, VF, RVW, WV2F, BIAS);
    attn_kernel<<<dim3(L, BN), 256, 0, stream>>>(padded, masks, pos3d, gamma, beta, tok,
                                                 RVW, WV2F, bv2,
                                                 Q, KF, VF, BIAS, out);
}

// Round 17
// 67.543 us; speedup vs baseline: 1.0999x; 1.0999x over previous
//
#include <hip/hip_runtime.h>
#include <hip/hip_bf16.h>
#include <math.h>

#define BN 32
#define L 128
#define D 128
#define TT 127
#define NH 8

typedef float f32x4 __attribute__((ext_vector_type(4)));
typedef short s16x8 __attribute__((ext_vector_type(8)));

__device__ __forceinline__ float gelu_sig(float x) {
    float e = __expf(-1.702f * x);
    return x * __builtin_amdgcn_rcpf(1.0f + e);
}
__device__ __forceinline__ unsigned short f2bf(float f) {
    __hip_bfloat16 h = __float2bfloat16(f);
    return *reinterpret_cast<unsigned short*>(&h);
}
__device__ __forceinline__ float bf2f(unsigned short v) {
    return __uint_as_float((unsigned)v << 16);
}

// ---------------- K1: qkv (blocks 0..383) + bias MLP (blocks 384..2431) ----------------
// Q -> f32 rows. K -> KF (bf16, B-fragment order of K^T). V -> VF (bf16, B-fragment).
__global__ __launch_bounds__(256)
void qkv_bias_kernel(const float* __restrict__ padded, const float* __restrict__ tok,
                     const float* __restrict__ Wq, const float* __restrict__ bq,
                     const float* __restrict__ Wk, const float* __restrict__ bk,
                     const float* __restrict__ Wv, const float* __restrict__ bv,
                     const float* __restrict__ Wb1, const float* __restrict__ bb1,
                     const float* __restrict__ Wb2, const float* __restrict__ bb2,
                     const float* __restrict__ Wv1, const float* __restrict__ bv1,
                     const float* __restrict__ Wv2,
                     const int* __restrict__ masks, const float* __restrict__ pos3d,
                     float* __restrict__ Qo, unsigned short* __restrict__ KF,
                     unsigned short* __restrict__ VF,
                     float* __restrict__ RVW, unsigned short* __restrict__ WV2F,
                     unsigned short* __restrict__ BIAS) {
    const int bid = blockIdx.x;
    const int tid = threadIdx.x;

    if (bid < 384) {
        // ---------------- qkv ----------------
        const int chunk = bid / 96;
        const int rem = bid % 96;
        const int mat = rem >> 5;
        const int s = rem & 31;
        const float* W = (mat == 0) ? Wq : (mat == 1) ? Wk : Wv;
        const float* bias = (mat == 0) ? bq : (mat == 1) ? bk : bv;

        __shared__ __align__(16) unsigned short Xs[32][136];
        {
            const int row = tid >> 3;
            const int colbase = (tid & 7) * 16;
            const int i = chunk * 32 + row;
            const float* src = (i == 0) ? tok : &padded[(size_t)s * TT * D + (size_t)(i - 1) * D];
#pragma unroll
            for (int k4 = 0; k4 < 4; ++k4) {
                float4 v = *(const float4*)&src[colbase + k4 * 4];
                unsigned lo = (unsigned)f2bf(v.x) | ((unsigned)f2bf(v.y) << 16);
                unsigned hi = (unsigned)f2bf(v.z) | ((unsigned)f2bf(v.w) << 16);
                *(uint2*)&Xs[row][colbase + k4 * 4] = make_uint2(lo, hi);
            }
        }
        __syncthreads();

        const int wave = tid >> 6;
        const int lane = tid & 63;
        const int hA = lane & 15;
        const int kg = lane >> 4;

        s16x8 afr[2][4];
#pragma unroll
        for (int m = 0; m < 2; ++m)
#pragma unroll
            for (int kt = 0; kt < 4; ++kt)
                afr[m][kt] = *(const s16x8*)&Xs[m * 16 + hA][kt * 32 + kg * 8];

        f32x4 acc[2][2];
#pragma unroll
        for (int m = 0; m < 2; ++m)
#pragma unroll
            for (int n = 0; n < 2; ++n) acc[m][n] = (f32x4){0.f, 0.f, 0.f, 0.f};

#pragma unroll
        for (int kt = 0; kt < 4; ++kt) {
#pragma unroll
            for (int n = 0; n < 2; ++n) {
                const int col = (2 * wave + n) * 16 + hA;
                s16x8 bw;
#pragma unroll
                for (int e = 0; e < 8; ++e)
                    bw[e] = (short)f2bf(W[(size_t)(kt * 32 + kg * 8 + e) * D + col]);
                acc[0][n] = __builtin_amdgcn_mfma_f32_16x16x32_bf16(afr[0][kt], bw, acc[0][n], 0, 0, 0);
                acc[1][n] = __builtin_amdgcn_mfma_f32_16x16x32_bf16(afr[1][kt], bw, acc[1][n], 0, 0, 0);
            }
        }

        if (mat == 0) {
#pragma unroll
            for (int n = 0; n < 2; ++n) {
                const int col = (2 * wave + n) * 16 + hA;
                const float bc = bias[col];
#pragma unroll
                for (int m = 0; m < 2; ++m)
#pragma unroll
                    for (int r = 0; r < 4; ++r) {
                        const int row = chunk * 32 + m * 16 + kg * 4 + r;
                        Qo[(size_t)s * L * D + (size_t)row * D + col] = acc[m][n][r] + bc;
                    }
            }
        } else {
            // ---- K/V: stage bf16 rows in LDS, then pack to fragment order ----
            __syncthreads();
#pragma unroll
            for (int n = 0; n < 2; ++n) {
                const int col = (2 * wave + n) * 16 + hA;
                const float bc = bias[col];
#pragma unroll
                for (int m = 0; m < 2; ++m)
#pragma unroll
                    for (int r = 0; r < 4; ++r)
                        Xs[m * 16 + kg * 4 + r][col] = f2bf(acc[m][n][r] + bc);
            }
            __syncthreads();
            if (mat == 2) {
#pragma unroll
                for (int pass = 0; pass < 2; ++pass) {
                    const int idx = pass * 256 + tid;
                    const int fl = idx >> 6, ln = idx & 63;
                    unsigned short v8[8];
#pragma unroll
                    for (int e = 0; e < 8; ++e)
                        v8[e] = Xs[(ln >> 4) * 8 + e][fl * 16 + (ln & 15)];
                    *(uint4*)&VF[(size_t)s * 16384 + ((size_t)(chunk * 8 + fl) * 64 + ln) * 8] = *(uint4*)v8;
                }
            } else {
#pragma unroll
                for (int pass = 0; pass < 2; ++pass) {
                    const int idx = pass * 256 + tid;
                    const int lf = idx >> 6, ln = idx & 63;
                    const int kt = lf >> 1, ngl = lf & 1;
                    uint4 v = *(const uint4*)&Xs[ngl * 16 + (ln & 15)][kt * 32 + (ln >> 4) * 8];
                    *(uint4*)&KF[(size_t)s * 16384 + ((size_t)(kt * 8 + 2 * chunk + ngl) * 64 + ln) * 8] = v;
                }
            }
        }

        if (bid == 0) {
            if (tid < 128) {
                const int cc = tid;
                RVW[cc * 8 + 0] = Wv1[0 * 128 + cc];
                RVW[cc * 8 + 1] = Wv1[1 * 128 + cc];
                RVW[cc * 8 + 2] = Wv1[2 * 128 + cc];
                RVW[cc * 8 + 3] = Wv1[3 * 128 + cc] + Wv1[4 * 128 + cc];
                RVW[cc * 8 + 4] = Wv1[5 * 128 + cc];
                RVW[cc * 8 + 5] = bv1[cc];
                RVW[cc * 8 + 6] = 0.f;
                RVW[cc * 8 + 7] = 0.f;
            }
            for (int idx = tid; idx < 16384; idx += 256) {
                int f = idx >> 9, r = idx & 511, ln = r >> 3, e = r & 7;
                int kt = f >> 3, ng = f & 7;
                int row = kt * 32 + (ln >> 4) * 8 + e;
                int col = ng * 16 + (ln & 15);
                WV2F[idx] = f2bf(Wv2[(size_t)row * D + col]);
            }
        }
    } else {
        // ---------------- bias MLP ----------------
        const int b2 = bid - 384;
        const int s = b2 >> 6;
        const int jp = b2 & 63;
        const int wv = tid >> 6;
        const int lane = tid & 63;
        const int j = jp * 2 + (wv >> 1);
        const int i = (wv & 1) * 64 + lane;

        if (j == 0) return;
        if (!masks[(size_t)s * TT + (j - 1)]) return;
        const float* pj = pos3d + ((size_t)s * TT + (j - 1)) * 3;
        const int im1 = (i > 0) ? (i - 1) : 0;
        const float* pi = pos3d + ((size_t)s * TT + im1) * 3;
        const float pix = (i > 0) ? pi[0] : 0.f;
        const float piy = (i > 0) ? pi[1] : 0.f;
        const float piz = (i > 0) ? pi[2] : 0.f;
        const float dx = pix - pj[0], dy = piy - pj[1], dz = piz - pj[2];
        const float dist2 = dx * dx + dy * dy + dz * dz;
        const float dist = sqrtf(dist2);

        float bias[NH];
#pragma unroll
        for (int hh = 0; hh < NH; ++hh) bias[hh] = 0.f;
#pragma unroll 2
        for (int u = 0; u < 64; ++u) {
            const float w0 = Wb1[u];
            const float w1 = Wb1[64 + u];
            const float w2 = Wb1[128 + u];
            const float w3 = Wb1[192 + u] + Wb1[256 + u];
            const float w4 = Wb1[320 + u];
            float hv = bb1[u];
            hv = fmaf(dx, w0, hv);
            hv = fmaf(dy, w1, hv);
            hv = fmaf(dz, w2, hv);
            hv = fmaf(dist, w3, hv);
            hv = fmaf(dist2, w4, hv);
            hv = gelu_sig(hv);
            const float* w2p = &Wb2[u * 8];
            bias[0] = fmaf(hv, w2p[0], bias[0]);
            bias[1] = fmaf(hv, w2p[1], bias[1]);
            bias[2] = fmaf(hv, w2p[2], bias[2]);
            bias[3] = fmaf(hv, w2p[3], bias[3]);
            bias[4] = fmaf(hv, w2p[4], bias[4]);
            bias[5] = fmaf(hv, w2p[5], bias[5]);
            bias[6] = fmaf(hv, w2p[6], bias[6]);
            bias[7] = fmaf(hv, w2p[7], bias[7]);
        }
        if (i > 0) {
            uint4 ow;
            ow.x = (unsigned)f2bf(bias[0] + bb2[0]) | ((unsigned)f2bf(bias[1] + bb2[1]) << 16);
            ow.y = (unsigned)f2bf(bias[2] + bb2[2]) | ((unsigned)f2bf(bias[3] + bb2[3]) << 16);
            ow.z = (unsigned)f2bf(bias[4] + bb2[4]) | ((unsigned)f2bf(bias[5] + bb2[5]) << 16);
            ow.w = (unsigned)f2bf(bias[6] + bb2[6]) | ((unsigned)f2bf(bias[7] + bb2[7]) << 16);
            *(uint4*)&BIAS[(((size_t)s * L + i) * L + j) * 8] = ow;   // i-major
        }
    }
}

// ---------------- K3: core per (s,i). grid (L, BN), block 256 (4 waves) ----------------
// Logits computed in-kernel via MFMA (block-diagonal Q-row A x KF); a1 via MFMA x VF.
__global__ __launch_bounds__(256, 4)
void attn_kernel(const float* __restrict__ padded, const int* __restrict__ masks,
                 const float* __restrict__ pos3d,
                 const float* __restrict__ gamma, const float* __restrict__ beta,
                 const float* __restrict__ tok,
                 const float* __restrict__ RVW,
                 const unsigned short* __restrict__ WV2F,
                 const float* __restrict__ bv2,
                 const float* __restrict__ Q,
                 const unsigned short* __restrict__ KF,
                 const unsigned short* __restrict__ VF,
                 const unsigned short* __restrict__ BIAS,
                 float* __restrict__ out) {
    const int i = blockIdx.x;
    const int s = blockIdx.y;
    const int tid = threadIdx.x;
    const int wave = tid >> 6;
    const int lane = tid & 63;
    const int hA = lane & 15;
    const int kg = lane >> 4;
    const int j = tid & 127;
    const int hbase = (tid >> 7) * 4;

    __shared__ float4 feat4_lds[144];
    __shared__ float  feat5_lds[L];
    __shared__ __align__(16) unsigned short qbf[128];
    __shared__ float  l_lds[NH][132];
    __shared__ unsigned short w_bf[NH][136];   // compacted normalized w
    __shared__ unsigned short wu_bf[NH][136];  // uncompacted normalized w
    __shared__ unsigned short gs_bf[NH][136];  // GS rows (bf16)
    __shared__ float  a12_lds[2][D];           // [0]=a1, [1]=a2
    __shared__ float  reds[4][NH];
    __shared__ float  red2[2][2];
    __shared__ unsigned long long kb_lds[2];
    __shared__ int    jmap_lds[128];

    // ---- early loads: mask + bias ----
    const int keep = (j == 0) ? 1 : masks[(size_t)s * TT + (j - 1)];
    const int ub = (i > 0) && (j > 0) && keep;
    uint2 braw = make_uint2(0u, 0u);
    if (ub) braw = *(const uint2*)&BIAS[(((size_t)s * L + i) * L + j) * 8 + hbase];

    const unsigned long long bal = __ballot(keep != 0);
    if (lane == 0 && wave < 2) kb_lds[wave] = bal;

    // ---- stage Q row (bf16) + relative features (threads 0-127) ----
    if (tid < 128) {
        qbf[tid] = f2bf(Q[((size_t)s * L + i) * D + tid]);
        float pix = 0.f, piy = 0.f, piz = 0.f;
        if (i > 0) { const float* pp = pos3d + ((size_t)s * TT + (i - 1)) * 3; pix = pp[0]; piy = pp[1]; piz = pp[2]; }
        float pjx = 0.f, pjy = 0.f, pjz = 0.f;
        if (tid > 0) { const float* pp = pos3d + ((size_t)s * TT + (tid - 1)) * 3; pjx = pp[0]; pjy = pp[1]; pjz = pp[2]; }
        const float dx = pix - pjx, dy = piy - pjy, dz = piz - pjz;
        const float dist2 = dx * dx + dy * dy + dz * dz;
        const float dist = sqrtf(dist2);
        feat4_lds[tid + (tid >> 3)] = make_float4(dx, dy, dz, dist);
        feat5_lds[tid] = dist2;
        jmap_lds[tid] = 0;
    }
    for (int idx = tid; idx < NH * 68; idx += 256) {
        ((unsigned*)w_bf)[idx] = 0u;
        ((unsigned*)wu_bf)[idx] = 0u;
    }
    __syncthreads();                       // A: qbf + kb ready

    const unsigned long long b0 = kb_lds[0];
    const int nk = __popcll(b0) + __popcll(kb_lds[1]);
    const int NK32 = (nk + 31) >> 5;
    int rank = 0;
    if (keep) {
        rank = __popcll(bal & ((1ull << lane) - 1)) + ((wave & 1) ? __popcll(b0) : 0);
        if (wave < 2) jmap_lds[rank] = j;
    }

    const int ng0 = 2 * wave;
    const unsigned short* KFs = KF + (size_t)s * 16384;
    const unsigned short* VFs = VF + (size_t)s * 16384;

    // ---- logits via MFMA: A = Q row masked to head slices (block-diagonal) ----
    {
        f32x4 accL[2];
        accL[0] = (f32x4){0.f, 0.f, 0.f, 0.f};
        accL[1] = (f32x4){0.f, 0.f, 0.f, 0.f};
#pragma unroll
        for (int kt = 0; kt < 4; ++kt) {
            const int hslice = kt * 2 + (kg >> 1);
            s16x8 qa;
#pragma unroll
            for (int e = 0; e < 8; ++e) qa[e] = 0;
            if (hA == hslice)
                qa = *(const s16x8*)&qbf[kt * 32 + kg * 8];
#pragma unroll
            for (int n = 0; n < 2; ++n) {
                s16x8 bk = *(const s16x8*)&KFs[((size_t)(kt * 8 + ng0 + n) * 64 + lane) * 8];
                accL[n] = __builtin_amdgcn_mfma_f32_16x16x32_bf16(qa, bk, accL[n], 0, 0, 0);
            }
        }
        if (lane < 32) {
#pragma unroll
            for (int n = 0; n < 2; ++n)
#pragma unroll
                for (int r = 0; r < 4; ++r)
                    l_lds[(lane >> 4) * 4 + r][(ng0 + n) * 16 + hA] = accL[n][r];
        }
    }
    __syncthreads();                       // B: l_lds ready

    // ---- softmax: 4 heads per thread-half ----
    float badd[4];
    badd[0] = bf2f((unsigned short)(braw.x & 0xffffu));
    badd[1] = bf2f((unsigned short)(braw.x >> 16));
    badd[2] = bf2f((unsigned short)(braw.y & 0xffffu));
    badd[3] = bf2f((unsigned short)(braw.y >> 16));
    float p4[4];
#pragma unroll
    for (int k = 0; k < 4; ++k) {
        float lv = fmaf(l_lds[hbase + k][j], 0.25f, badd[k]);
        p4[k] = keep ? __expf(lv) : 0.f;
    }
#pragma unroll
    for (int k = 0; k < 4; ++k) {
        float v = p4[k];
        for (int off = 32; off >= 1; off >>= 1) v += __shfl_xor(v, off, 64);
        if (lane == 0) reds[wave][hbase + k] = v;
    }
    __syncthreads();                       // C: reds ready
    if (keep) {
        const int pb = (tid >> 7) * 2;
#pragma unroll
        for (int k = 0; k < 4; ++k) {
            const int hh = hbase + k;
            float inv = __builtin_amdgcn_rcpf(reds[pb][hh] + reds[pb + 1][hh]);
            unsigned short wn = f2bf(p4[k] * inv);
            w_bf[hh][rank] = wn;
            wu_bf[hh][j] = wn;
        }
    }
    __syncthreads();                       // D: w ready

    // ---- a1 = W · V via MFMA (uncompacted w, prepacked V) — all i ----
    f32x4 acc1[2];
    acc1[0] = (f32x4){0.f, 0.f, 0.f, 0.f};
    acc1[1] = (f32x4){0.f, 0.f, 0.f, 0.f};
#pragma unroll
    for (int kt = 0; kt < 4; ++kt) {
        s16x8 wuf;
#pragma unroll
        for (int e = 0; e < 8; ++e) wuf[e] = 0;
        if (hA < NH)
            wuf = *(const s16x8*)&wu_bf[hA][kt * 32 + kg * 8];
#pragma unroll
        for (int n = 0; n < 2; ++n) {
            const int f = kt * 8 + ng0 + n;
            s16x8 bw = *(const s16x8*)&VFs[((size_t)f * 64 + lane) * 8];
            acc1[n] = __builtin_amdgcn_mfma_f32_16x16x32_bf16(wuf, bw, acc1[n], 0, 0, 0);
        }
    }
#pragma unroll
    for (int n = 0; n < 2; ++n) {
        const int f = ng0 + n;
        if (kg == (f >> 2)) a12_lds[0][f * 16 + hA] = acc1[n][f & 3];
    }

    if (i > 0) {
        float rvw[2][6];
#pragma unroll
        for (int n = 0; n < 2; ++n) {
            const int c = (ng0 + n) * 16 + hA;
            float4 ra = *(const float4*)&RVW[(size_t)c * 8 + 0];
            rvw[n][0] = ra.x; rvw[n][1] = ra.y; rvw[n][2] = ra.z; rvw[n][3] = ra.w;
            rvw[n][4] = RVW[(size_t)c * 8 + 4];
            rvw[n][5] = RVW[(size_t)c * 8 + 5];
        }

        f32x4 accG[2];
#pragma unroll
        for (int n = 0; n < 2; ++n) accG[n] = (f32x4){0.f, 0.f, 0.f, 0.f};

#pragma unroll
        for (int kt = 0; kt < 4; ++kt) {
            if (kt >= NK32) break;
            s16x8 wf;
#pragma unroll
            for (int e = 0; e < 8; ++e) wf[e] = 0;
            if (hA < NH) {
                wf = *(const s16x8*)&w_bf[hA][kt * 32 + kg * 8];
                if (kt == 0 && kg == 0) wf[0] = 0;   // exclude j==0 (rank 0)
            }
            s16x8 bfr[2];
#pragma unroll
            for (int e = 0; e < 8; ++e) {
                const int jj = jmap_lds[kt * 32 + kg * 8 + e];
                float4 fa = feat4_lds[jj + (jj >> 3)];
                float f5 = feat5_lds[jj];
#pragma unroll
                for (int n = 0; n < 2; ++n) {
                    float hv = rvw[n][5];
                    hv = fmaf(fa.x, rvw[n][0], hv);
                    hv = fmaf(fa.y, rvw[n][1], hv);
                    hv = fmaf(fa.z, rvw[n][2], hv);
                    hv = fmaf(fa.w, rvw[n][3], hv);
                    hv = fmaf(f5,  rvw[n][4], hv);
                    bfr[n][e] = (short)f2bf(gelu_sig(hv));
                }
            }
#pragma unroll
            for (int n = 0; n < 2; ++n)
                accG[n] = __builtin_amdgcn_mfma_f32_16x16x32_bf16(wf, bfr[n], accG[n], 0, 0, 0);
        }

        // GS rows 0..7 live in lanes 0..31 (D-layout row=(lane>>4)*4+reg)
        if (lane < 32) {
#pragma unroll
            for (int n = 0; n < 2; ++n)
#pragma unroll
                for (int r = 0; r < 4; ++r)
                    gs_bf[(lane >> 4) * 4 + r][(ng0 + n) * 16 + hA] = f2bf(accG[n][r]);
        }
        __syncthreads();                   // E

        // ---- a2 = GS @ Wv2 via MFMA (2 col-frags per wave) ----
        f32x4 acc2[2];
#pragma unroll
        for (int n = 0; n < 2; ++n) acc2[n] = (f32x4){0.f, 0.f, 0.f, 0.f};
#pragma unroll
        for (int kt = 0; kt < 4; ++kt) {
            s16x8 gf;
#pragma unroll
            for (int e = 0; e < 8; ++e) gf[e] = 0;
            if (hA < NH)
                gf = *(const s16x8*)&gs_bf[hA][kt * 32 + kg * 8];
#pragma unroll
            for (int n = 0; n < 2; ++n) {
                const int f = kt * 8 + ng0 + n;
                s16x8 bw = *(const s16x8*)&WV2F[((size_t)f * 64 + lane) * 8];
                acc2[n] = __builtin_amdgcn_mfma_f32_16x16x32_bf16(gf, bw, acc2[n], 0, 0, 0);
            }
        }
#pragma unroll
        for (int n = 0; n < 2; ++n) {
            const int f = ng0 + n;
            if (kg == (f >> 2)) a12_lds[1][f * 16 + hA] = acc2[n][f & 3];
        }
        __syncthreads();                   // F

        if (tid < 128) {
            const float S1 = 1.0f - bf2f(wu_bf[tid >> 4][0]);
            const size_t o = (size_t)s * TT * D + (size_t)(i - 1) * D + tid;
            out[o] = a12_lds[0][tid] + a12_lds[1][tid] + S1 * bv2[tid] + padded[o];
        }
    } else {
        // ---- cls row: a2 == 0; a1 from MFMA + layernorm ----
        __syncthreads();                   // E

        float st = 0.f;
        if (tid < 128) {
            st = a12_lds[0][tid] + tok[tid];
            float sum = st, sum2 = st * st;
            for (int off = 32; off >= 1; off >>= 1) {
                sum += __shfl_xor(sum, off, 64);
                sum2 += __shfl_xor(sum2, off, 64);
            }
            if (lane == 0) { red2[wave][0] = sum; red2[wave][1] = sum2; }
        }
        __syncthreads();
        if (tid < 128) {
            float sum = red2[0][0] + red2[1][0];
            float sum2 = red2[0][1] + red2[1][1];
            const float mu = sum * (1.0f / 128.0f);
            const float var = sum2 * (1.0f / 128.0f) - mu * mu;
            const float y = (st - mu) * rsqrtf(var + 1e-5f) * gamma[tid] + beta[tid];
            out[(size_t)BN * TT * D + (size_t)s * D + tid] = y;
        }
    }
}

extern "C" void kernel_launch(void* const* d_in, const int* in_sizes, int n_in,
                              void* d_out, int out_size, void* d_ws, size_t ws_size,
                              hipStream_t stream) {
    const float* padded = (const float*)d_in[0];
    const int*   masks  = (const int*)d_in[1];
    const float* pos3d  = (const float*)d_in[2];
    const float* Wq = (const float*)d_in[3];
    const float* bq = (const float*)d_in[4];
    const float* Wk = (const float*)d_in[5];
    const float* bk = (const float*)d_in[6];
    const float* Wv = (const float*)d_in[7];
    const float* bv = (const float*)d_in[8];
    const float* gamma = (const float*)d_in[9];
    const float* beta  = (const float*)d_in[10];
    const float* tok   = (const float*)d_in[11];
    const float* Wb1 = (const float*)d_in[12];
    const float* bb1 = (const float*)d_in[13];
    const float* Wb2 = (const float*)d_in[14];
    const float* bb2 = (const float*)d_in[15];
    const float* Wv1 = (const float*)d_in[16];
    const float* bv1 = (const float*)d_in[17];
    const float* Wv2 = (const float*)d_in[18];
    const float* bv2 = (const float*)d_in[19];
    float* out = (float*)d_out;

    float* Q  = (float*)d_ws;
    unsigned short* KF = (unsigned short*)(Q + (size_t)BN * L * D);
    unsigned short* VF = KF + (size_t)BN * L * D;
    unsigned short* BIAS = VF + (size_t)BN * L * D;
    float* RVW = (float*)(BIAS + (size_t)BN * L * L * NH);
    unsigned short* WV2F = (unsigned short*)(RVW + 128 * 8);

    qkv_bias_kernel<<<dim3(384 + BN * 64), 256, 0, stream>>>(
        padded, tok, Wq, bq, Wk, bk, Wv, bv, Wb1, bb1, Wb2, bb2, Wv1, bv1, Wv2,
        masks, pos3d, Q, KF, VF, RVW, WV2F, BIAS);
    attn_kernel<<<dim3(L, BN), 256, 0, stream>>>(padded, masks, pos3d, gamma, beta, tok,
                                                 RVW, WV2F, bv2,
                                                 Q, KF, VF, BIAS, out);
}